// Round 1
// baseline (307.377 us; speedup 1.0000x reference)
//
#include <hip/hip_runtime.h>

typedef __bf16 bf16x8 __attribute__((ext_vector_type(8)));
typedef float f32x4 __attribute__((ext_vector_type(4)));

#define MFMA16(a,b,c) __builtin_amdgcn_mfma_f32_16x16x32_bf16((a),(b),(c),0,0,0)

// Problem constants: B=8 S=1024 IN=512 ORIG=64 E=512 H=8 hd=64
// xc: [8192][576]  Wqkv: [1536][576]  Wo: [512][512]
// q_ws/k_ws: [64(bh)][1024(s)][64(d)] bf16 ; vt_ws: [64(bh)][64(d)][1024(s)] bf16
// values: [8192][512] bf16

__global__ __launch_bounds__(256) void k_convert(
    const float* __restrict__ x, const float* __restrict__ inp,
    const float* __restrict__ Wqkv, const float* __restrict__ Wo,
    __bf16* __restrict__ xc, __bf16* __restrict__ wq, __bf16* __restrict__ wo)
{
    unsigned i = blockIdx.x * 256u + threadIdx.x;
    const unsigned n1 = 8192u * 576u;        // 4,718,592
    const unsigned n2 = 1536u * 576u;        //   884,736
    if (i < n1) {
        unsigned m = i / 576u, k = i - m * 576u;
        float v = (k < 512u) ? x[(size_t)m * 512u + k] : inp[(size_t)m * 64u + (k - 512u)];
        xc[i] = (__bf16)v;
    } else if (i < n1 + n2) {
        wq[i - n1] = (__bf16)Wqkv[i - n1];
    } else {
        wo[i - n1 - n2] = (__bf16)Wo[i - n1 - n2];
    }
}

// ---------------- QKV GEMM: [8192x576] @ [576x1536] -> scatter q/k/vt ----------------
__global__ __launch_bounds__(256) void k_qkv_gemm(
    const __bf16* __restrict__ A,    // [8192][576]
    const __bf16* __restrict__ W,    // [1536][576]
    const float* __restrict__ bias,  // [1536]
    __bf16* __restrict__ q_ws, __bf16* __restrict__ k_ws, __bf16* __restrict__ vt_ws)
{
    const int K = 576;
    __shared__ __align__(16) __bf16 As[64][40];  // +8 pad: breaks 64B-stride bank aliasing
    __shared__ __align__(16) __bf16 Bs[64][40];
    int m0 = blockIdx.x * 64, n0 = blockIdx.y * 64;
    int t = threadIdx.x, w = t >> 6, l = t & 63;
    int srow = t >> 2, scol = (t & 3) * 8;
    f32x4 acc[4] = {};
    for (int k0 = 0; k0 < K; k0 += 32) {
        *(bf16x8*)&As[srow][scol] = *(const bf16x8*)&A[(size_t)(m0 + srow) * K + k0 + scol];
        *(bf16x8*)&Bs[srow][scol] = *(const bf16x8*)&W[(size_t)(n0 + srow) * K + k0 + scol];
        __syncthreads();
        bf16x8 af = *(const bf16x8*)&As[w * 16 + (l & 15)][(l >> 4) * 8];
#pragma unroll
        for (int nti = 0; nti < 4; ++nti) {
            bf16x8 bfr = *(const bf16x8*)&Bs[nti * 16 + (l & 15)][(l >> 4) * 8];
            acc[nti] = MFMA16(af, bfr, acc[nti]);
        }
        __syncthreads();
    }
    int col = l & 15, rb = (l >> 4) * 4;
#pragma unroll
    for (int nti = 0; nti < 4; ++nti) {
        int n = n0 + nti * 16 + col;
        int h = n / 192, jj = n % 192, part = jj >> 6, d = jj & 63;
#pragma unroll
        for (int j = 0; j < 4; ++j) {
            int m = m0 + w * 16 + rb + j;
            float v = acc[nti][j] + bias[n];
            int b = m >> 10, s = m & 1023;
            size_t bh = (size_t)(b * 8 + h);
            if (part == 0)      q_ws[(bh * 1024 + s) * 64 + d] = (__bf16)(v * 0.125f);
            else if (part == 1) k_ws[(bh * 1024 + s) * 64 + d] = (__bf16)v;
            else                vt_ws[(bh * 64 + d) * 1024 + s] = (__bf16)v;
        }
    }
}

// ---------------- fused attention: logits->softmax->probs(out)+PV ----------------
__global__ __launch_bounds__(256) void k_attn(
    const __bf16* __restrict__ q_ws, const __bf16* __restrict__ k_ws,
    const __bf16* __restrict__ vt_ws,
    float* __restrict__ att_out, __bf16* __restrict__ values)
{
    __shared__ __align__(16) float Ls[32][1028];   // +4 f32 pad per row
    __shared__ __align__(16) __bf16 Qs[32][72];    // +8 bf16 pad
    int qt = blockIdx.x, bh = blockIdx.y;
    int q0 = qt * 32;
    int t = threadIdx.x, w = t >> 6, l = t & 63;

    {   // stage Q tile [32][64]
        int r = t >> 3, c = (t & 7) * 8;
        *(bf16x8*)&Qs[r][c] = *(const bf16x8*)&q_ws[((size_t)bh * 1024 + q0 + r) * 64 + c];
    }
    __syncthreads();

    bf16x8 qa[2][2];
#pragma unroll
    for (int mt = 0; mt < 2; ++mt)
#pragma unroll
        for (int ks = 0; ks < 2; ++ks)
            qa[mt][ks] = *(const bf16x8*)&Qs[mt * 16 + (l & 15)][ks * 32 + (l >> 4) * 8];

    // QK^T: wave w covers cols [w*256, w*256+256)
    const __bf16* Kb = k_ws + (size_t)bh * 1024 * 64;
#pragma unroll 2
    for (int ct = 0; ct < 16; ++ct) {
        int col0 = w * 256 + ct * 16;
        const __bf16* kp = Kb + (size_t)(col0 + (l & 15)) * 64 + (l >> 4) * 8;
        bf16x8 kb0 = *(const bf16x8*)kp;
        bf16x8 kb1 = *(const bf16x8*)(kp + 32);
#pragma unroll
        for (int mt = 0; mt < 2; ++mt) {
            f32x4 acc = {};
            acc = MFMA16(qa[mt][0], kb0, acc);
            acc = MFMA16(qa[mt][1], kb1, acc);
#pragma unroll
            for (int j = 0; j < 4; ++j)
                Ls[mt * 16 + (l >> 4) * 4 + j][col0 + (l & 15)] = acc[j];
        }
    }
    __syncthreads();

    // softmax: 8 threads per row, 128 cols each; write probs to global + in-place LDS
    {
        int r = t >> 3;
        int c0 = (t & 7) * 128;
        float* Lrow = &Ls[r][c0];
        float mx = -3.4e38f;
#pragma unroll 8
        for (int i = 0; i < 128; i += 4) {
            float4 v = *(float4*)&Lrow[i];
            mx = fmaxf(mx, fmaxf(fmaxf(v.x, v.y), fmaxf(v.z, v.w)));
        }
#pragma unroll
        for (int off = 1; off < 8; off <<= 1) mx = fmaxf(mx, __shfl_xor(mx, off, 8));
        float sum = 0.f;
#pragma unroll 8
        for (int i = 0; i < 128; i += 4) {
            float4 v = *(float4*)&Lrow[i];
            sum += __expf(v.x - mx) + __expf(v.y - mx) + __expf(v.z - mx) + __expf(v.w - mx);
        }
#pragma unroll
        for (int off = 1; off < 8; off <<= 1) sum += __shfl_xor(sum, off, 8);
        float inv = 1.f / sum;
        float* gout = att_out + ((size_t)bh * 1024 + q0 + r) * 1024 + c0;
#pragma unroll 4
        for (int i = 0; i < 128; i += 4) {
            float4 v = *(float4*)&Lrow[i];
            float4 p;
            p.x = __expf(v.x - mx) * inv;
            p.y = __expf(v.y - mx) * inv;
            p.z = __expf(v.z - mx) * inv;
            p.w = __expf(v.w - mx) * inv;
            *(float4*)&Lrow[i] = p;
            *(float4*)&gout[i] = p;
        }
    }
    __syncthreads();

    // PV: wave w covers d-cols [w*16, w*16+16)
    const __bf16* Vb = vt_ws + (size_t)bh * 64 * 1024;
    const __bf16* vp0 = Vb + (size_t)(w * 16 + (l & 15)) * 1024 + (l >> 4) * 8;
    f32x4 vacc[2] = {};
#pragma unroll 2
    for (int ks = 0; ks < 32; ++ks) {
        bf16x8 vb = *(const bf16x8*)(vp0 + ks * 32);
#pragma unroll
        for (int mt = 0; mt < 2; ++mt) {
            const float* pp = &Ls[mt * 16 + (l & 15)][ks * 32 + (l >> 4) * 8];
            float4 p0 = *(const float4*)pp;
            float4 p1 = *(const float4*)(pp + 4);
            bf16x8 pa;
            pa[0] = (__bf16)p0.x; pa[1] = (__bf16)p0.y; pa[2] = (__bf16)p0.z; pa[3] = (__bf16)p0.w;
            pa[4] = (__bf16)p1.x; pa[5] = (__bf16)p1.y; pa[6] = (__bf16)p1.z; pa[7] = (__bf16)p1.w;
            vacc[mt] = MFMA16(pa, vb, vacc[mt]);
        }
    }
    int b = bh >> 3, h = bh & 7;
#pragma unroll
    for (int mt = 0; mt < 2; ++mt)
#pragma unroll
        for (int j = 0; j < 4; ++j) {
            int s = q0 + mt * 16 + (l >> 4) * 4 + j;
            values[((size_t)b * 1024 + s) * 512 + h * 64 + (w * 16 + (l & 15))] = (__bf16)vacc[mt][j];
        }
}

// ---------------- output GEMM: [8192x512] @ [512x512] + bias -> o ----------------
__global__ __launch_bounds__(256) void k_out_gemm(
    const __bf16* __restrict__ A,    // [8192][512] values
    const __bf16* __restrict__ W,    // [512][512]
    const float* __restrict__ bias,  // [512]
    float* __restrict__ out)         // [8192][512]
{
    const int K = 512;
    __shared__ __align__(16) __bf16 As[64][40];
    __shared__ __align__(16) __bf16 Bs[64][40];
    int m0 = blockIdx.x * 64, n0 = blockIdx.y * 64;
    int t = threadIdx.x, w = t >> 6, l = t & 63;
    int srow = t >> 2, scol = (t & 3) * 8;
    f32x4 acc[4] = {};
    for (int k0 = 0; k0 < K; k0 += 32) {
        *(bf16x8*)&As[srow][scol] = *(const bf16x8*)&A[(size_t)(m0 + srow) * K + k0 + scol];
        *(bf16x8*)&Bs[srow][scol] = *(const bf16x8*)&W[(size_t)(n0 + srow) * K + k0 + scol];
        __syncthreads();
        bf16x8 af = *(const bf16x8*)&As[w * 16 + (l & 15)][(l >> 4) * 8];
#pragma unroll
        for (int nti = 0; nti < 4; ++nti) {
            bf16x8 bfr = *(const bf16x8*)&Bs[nti * 16 + (l & 15)][(l >> 4) * 8];
            acc[nti] = MFMA16(af, bfr, acc[nti]);
        }
        __syncthreads();
    }
    int col = l & 15, rb = (l >> 4) * 4;
#pragma unroll
    for (int nti = 0; nti < 4; ++nti) {
        int n = n0 + nti * 16 + col;
        float bn = bias[n];
#pragma unroll
        for (int j = 0; j < 4; ++j) {
            int m = m0 + w * 16 + rb + j;
            out[(size_t)m * 512 + n] = acc[nti][j] + bn;
        }
    }
}

extern "C" void kernel_launch(void* const* d_in, const int* in_sizes, int n_in,
                              void* d_out, int out_size, void* d_ws, size_t ws_size,
                              hipStream_t stream)
{
    const float* x    = (const float*)d_in[0];
    const float* inp  = (const float*)d_in[1];
    const float* Wqkv = (const float*)d_in[2];
    const float* bqkv = (const float*)d_in[3];
    const float* Wo   = (const float*)d_in[4];
    const float* bo   = (const float*)d_in[5];

    float* out_o   = (float*)d_out;                    // [8,1024,512]
    float* out_att = out_o + (size_t)8 * 1024 * 512;   // [8,8,1024,1024]

    char* ws = (char*)d_ws;
    __bf16* xc    = (__bf16*)(ws + 0);         //  9,437,184 B
    __bf16* wq    = (__bf16*)(ws + 9437184);   //  1,769,472 B
    __bf16* wo    = (__bf16*)(ws + 11206656);  //    524,288 B
    __bf16* q_ws  = (__bf16*)(ws + 11730944);  //  8,388,608 B
    __bf16* k_ws  = (__bf16*)(ws + 20119552);  //  8,388,608 B
    __bf16* vt_ws = (__bf16*)(ws + 28508160);  //  8,388,608 B
    __bf16* vals  = (__bf16*)(ws + 36896768);  //  8,388,608 B  (total ~45.3 MB)

    k_convert<<<22912, 256, 0, stream>>>(x, inp, Wqkv, Wo, xc, wq, wo);
    k_qkv_gemm<<<dim3(128, 24), 256, 0, stream>>>(xc, wq, bqkv, q_ws, k_ws, vt_ws);
    k_attn<<<dim3(32, 64), 256, 0, stream>>>(q_ws, k_ws, vt_ws, out_att, vals);
    k_out_gemm<<<dim3(128, 8), 256, 0, stream>>>(vals, wo, bo, out_o);
}

// Round 2
// 221.131 us; speedup vs baseline: 1.3900x; 1.3900x over previous
//
#include <hip/hip_runtime.h>

typedef __bf16 bf16x8 __attribute__((ext_vector_type(8)));
typedef __bf16 bf16x4 __attribute__((ext_vector_type(4)));
typedef float f32x4 __attribute__((ext_vector_type(4)));

#define MFMA16(a,b,c) __builtin_amdgcn_mfma_f32_16x16x32_bf16((a),(b),(c),0,0,0)

// Problem constants: B=8 S=1024 IN=512 ORIG=64 E=512 H=8 hd=64
// xc: [8192][576]  Wqkv: [1536][576]  Wo: [512][512]
// q_ws/k_ws: [64(bh)][1024(s)][64(d)] bf16 ; vt_ws: [64(bh)][64(d)][1024(s)] bf16
// values: [8192][512] bf16

__global__ __launch_bounds__(256) void k_convert(
    const float* __restrict__ x, const float* __restrict__ inp,
    const float* __restrict__ Wqkv, const float* __restrict__ Wo,
    __bf16* __restrict__ xc, __bf16* __restrict__ wq, __bf16* __restrict__ wo)
{
    unsigned i = blockIdx.x * 256u + threadIdx.x;
    const unsigned n1 = 8192u * 576u;        // 4,718,592
    const unsigned n2 = 1536u * 576u;        //   884,736
    if (i < n1) {
        unsigned m = i / 576u, k = i - m * 576u;
        float v = (k < 512u) ? x[(size_t)m * 512u + k] : inp[(size_t)m * 64u + (k - 512u)];
        xc[i] = (__bf16)v;
    } else if (i < n1 + n2) {
        wq[i - n1] = (__bf16)Wqkv[i - n1];
    } else {
        wo[i - n1 - n2] = (__bf16)Wo[i - n1 - n2];
    }
}

// ---------------- QKV GEMM: [8192x576] @ [576x1536] -> scatter q/k/vt ----------------
__global__ __launch_bounds__(256) void k_qkv_gemm(
    const __bf16* __restrict__ A,    // [8192][576]
    const __bf16* __restrict__ W,    // [1536][576]
    const float* __restrict__ bias,  // [1536]
    __bf16* __restrict__ q_ws, __bf16* __restrict__ k_ws, __bf16* __restrict__ vt_ws)
{
    const int K = 576;
    __shared__ __align__(16) __bf16 As[64][40];
    __shared__ __align__(16) __bf16 Bs[64][40];
    int m0 = blockIdx.x * 64, n0 = blockIdx.y * 64;
    int t = threadIdx.x, w = t >> 6, l = t & 63;
    int srow = t >> 2, scol = (t & 3) * 8;
    f32x4 acc[4] = {};
    for (int k0 = 0; k0 < K; k0 += 32) {
        *(bf16x8*)&As[srow][scol] = *(const bf16x8*)&A[(size_t)(m0 + srow) * K + k0 + scol];
        *(bf16x8*)&Bs[srow][scol] = *(const bf16x8*)&W[(size_t)(n0 + srow) * K + k0 + scol];
        __syncthreads();
        bf16x8 af = *(const bf16x8*)&As[w * 16 + (l & 15)][(l >> 4) * 8];
#pragma unroll
        for (int nti = 0; nti < 4; ++nti) {
            bf16x8 bfr = *(const bf16x8*)&Bs[nti * 16 + (l & 15)][(l >> 4) * 8];
            acc[nti] = MFMA16(af, bfr, acc[nti]);
        }
        __syncthreads();
    }
    int col = l & 15, rb = (l >> 4) * 4;
#pragma unroll
    for (int nti = 0; nti < 4; ++nti) {
        int n = n0 + nti * 16 + col;
        int h = n / 192, jj = n % 192, part = jj >> 6, d = jj & 63;
#pragma unroll
        for (int j = 0; j < 4; ++j) {
            int m = m0 + w * 16 + rb + j;
            float v = acc[nti][j] + bias[n];
            int b = m >> 10, s = m & 1023;
            size_t bh = (size_t)(b * 8 + h);
            if (part == 0)      q_ws[(bh * 1024 + s) * 64 + d] = (__bf16)(v * 0.125f);
            else if (part == 1) k_ws[(bh * 1024 + s) * 64 + d] = (__bf16)v;
            else                vt_ws[(bh * 64 + d) * 1024 + s] = (__bf16)v;
        }
    }
}

// ---------------- fused attention v2: 16-row q-tile, wave-per-row softmax ----------------
__global__ __launch_bounds__(256) void k_attn(
    const __bf16* __restrict__ q_ws, const __bf16* __restrict__ k_ws,
    const __bf16* __restrict__ vt_ws,
    float* __restrict__ att_out, __bf16* __restrict__ values)
{
    __shared__ __align__(16) float Ls[16][1028];   // 65,792 B -> 2 blocks/CU
    __shared__ __align__(16) __bf16 Qs[16][72];

    // bijective XCD swizzle: consecutive work for one bh stays on one XCD
    int bid = blockIdx.x;                  // grid = 4096 (64 bh x 64 q-tiles)
    int nid = (bid & 7) * 512 + (bid >> 3);
    int bh = nid >> 6, qt = nid & 63;
    int q0 = qt * 16;
    int t = threadIdx.x, w = t >> 6, l = t & 63;

    if (t < 128) {  // stage Q tile [16][64]
        int r = t >> 3, c = (t & 7) * 8;
        *(bf16x8*)&Qs[r][c] = *(const bf16x8*)&q_ws[((size_t)bh * 1024 + q0 + r) * 64 + c];
    }
    __syncthreads();

    bf16x8 qa[2];
#pragma unroll
    for (int ks = 0; ks < 2; ++ks)
        qa[ks] = *(const bf16x8*)&Qs[l & 15][ks * 32 + (l >> 4) * 8];

    // QK^T: wave w covers cols [w*256, w*256+256)
    const __bf16* Kb = k_ws + (size_t)bh * 1024 * 64;
#pragma unroll 4
    for (int ct = 0; ct < 16; ++ct) {
        int col0 = w * 256 + ct * 16;
        const __bf16* kp = Kb + (size_t)(col0 + (l & 15)) * 64 + (l >> 4) * 8;
        bf16x8 kb0 = *(const bf16x8*)kp;
        bf16x8 kb1 = *(const bf16x8*)(kp + 32);
        f32x4 acc = {};
        acc = MFMA16(qa[0], kb0, acc);
        acc = MFMA16(qa[1], kb1, acc);
#pragma unroll
        for (int j = 0; j < 4; ++j)
            Ls[(l >> 4) * 4 + j][col0 + (l & 15)] = acc[j];
    }
    __syncthreads();

    // softmax: wave w -> rows [w*4, w*4+4); lane l owns cols it*256 + l*4 (stride-1, coalesced)
#pragma unroll
    for (int rr = 0; rr < 4; ++rr) {
        int r = w * 4 + rr;
        float* Lrow = Ls[r];
        f32x4 v[4];
#pragma unroll
        for (int it = 0; it < 4; ++it)
            v[it] = *(f32x4*)&Lrow[it * 256 + l * 4];
        float mx = -3.4e38f;
#pragma unroll
        for (int it = 0; it < 4; ++it)
            mx = fmaxf(mx, fmaxf(fmaxf(v[it][0], v[it][1]), fmaxf(v[it][2], v[it][3])));
#pragma unroll
        for (int off = 1; off < 64; off <<= 1) mx = fmaxf(mx, __shfl_xor(mx, off));
        float sum = 0.f;
#pragma unroll
        for (int it = 0; it < 4; ++it) {
#pragma unroll
            for (int j = 0; j < 4; ++j) {
                v[it][j] = __expf(v[it][j] - mx);
                sum += v[it][j];
            }
        }
#pragma unroll
        for (int off = 1; off < 64; off <<= 1) sum += __shfl_xor(sum, off);
        float inv = 1.f / sum;
        float* gout = att_out + ((size_t)bh * 1024 + q0 + r) * 1024;
#pragma unroll
        for (int it = 0; it < 4; ++it) {
            f32x4 p = v[it] * inv;
            *(f32x4*)&gout[it * 256 + l * 4] = p;
            bf16x4 pb;
            pb[0] = (__bf16)p[0]; pb[1] = (__bf16)p[1];
            pb[2] = (__bf16)p[2]; pb[3] = (__bf16)p[3];
            *(bf16x4*)&Lrow[it * 128 + l * 2] = pb;   // packed bf16 probs, in place
        }
    }
    __syncthreads();

    // PV: wave w covers d-cols [w*16, w*16+16); probs read as bf16 directly
    const __bf16* Vb = vt_ws + (size_t)bh * 64 * 1024;
    const __bf16* vp0 = Vb + (size_t)(w * 16 + (l & 15)) * 1024 + (l >> 4) * 8;
    f32x4 vacc = {};
#pragma unroll 4
    for (int ks = 0; ks < 32; ++ks) {
        bf16x8 vb = *(const bf16x8*)(vp0 + ks * 32);
        bf16x8 pa = *(const bf16x8*)&Ls[l & 15][ks * 16 + (l >> 4) * 4];
        vacc = MFMA16(pa, vb, vacc);
    }
    int b = bh >> 3, h = bh & 7;
#pragma unroll
    for (int j = 0; j < 4; ++j) {
        int s = q0 + (l >> 4) * 4 + j;
        values[((size_t)b * 1024 + s) * 512 + h * 64 + (w * 16 + (l & 15))] = (__bf16)vacc[j];
    }
}

// ---------------- output GEMM: [8192x512] @ [512x512] + bias -> o ----------------
__global__ __launch_bounds__(256) void k_out_gemm(
    const __bf16* __restrict__ A,    // [8192][512] values
    const __bf16* __restrict__ W,    // [512][512]
    const float* __restrict__ bias,  // [512]
    float* __restrict__ out)         // [8192][512]
{
    const int K = 512;
    __shared__ __align__(16) __bf16 As[64][40];
    __shared__ __align__(16) __bf16 Bs[64][40];
    int m0 = blockIdx.x * 64, n0 = blockIdx.y * 64;
    int t = threadIdx.x, w = t >> 6, l = t & 63;
    int srow = t >> 2, scol = (t & 3) * 8;
    f32x4 acc[4] = {};
    for (int k0 = 0; k0 < K; k0 += 32) {
        *(bf16x8*)&As[srow][scol] = *(const bf16x8*)&A[(size_t)(m0 + srow) * K + k0 + scol];
        *(bf16x8*)&Bs[srow][scol] = *(const bf16x8*)&W[(size_t)(n0 + srow) * K + k0 + scol];
        __syncthreads();
        bf16x8 af = *(const bf16x8*)&As[w * 16 + (l & 15)][(l >> 4) * 8];
#pragma unroll
        for (int nti = 0; nti < 4; ++nti) {
            bf16x8 bfr = *(const bf16x8*)&Bs[nti * 16 + (l & 15)][(l >> 4) * 8];
            acc[nti] = MFMA16(af, bfr, acc[nti]);
        }
        __syncthreads();
    }
    int col = l & 15, rb = (l >> 4) * 4;
#pragma unroll
    for (int nti = 0; nti < 4; ++nti) {
        int n = n0 + nti * 16 + col;
        float bn = bias[n];
#pragma unroll
        for (int j = 0; j < 4; ++j) {
            int m = m0 + w * 16 + rb + j;
            out[(size_t)m * 512 + n] = acc[nti][j] + bn;
        }
    }
}

extern "C" void kernel_launch(void* const* d_in, const int* in_sizes, int n_in,
                              void* d_out, int out_size, void* d_ws, size_t ws_size,
                              hipStream_t stream)
{
    const float* x    = (const float*)d_in[0];
    const float* inp  = (const float*)d_in[1];
    const float* Wqkv = (const float*)d_in[2];
    const float* bqkv = (const float*)d_in[3];
    const float* Wo   = (const float*)d_in[4];
    const float* bo   = (const float*)d_in[5];

    float* out_o   = (float*)d_out;                    // [8,1024,512]
    float* out_att = out_o + (size_t)8 * 1024 * 512;   // [8,8,1024,1024]

    char* ws = (char*)d_ws;
    __bf16* xc    = (__bf16*)(ws + 0);         //  9,437,184 B
    __bf16* wq    = (__bf16*)(ws + 9437184);   //  1,769,472 B
    __bf16* wo    = (__bf16*)(ws + 11206656);  //    524,288 B
    __bf16* q_ws  = (__bf16*)(ws + 11730944);  //  8,388,608 B
    __bf16* k_ws  = (__bf16*)(ws + 20119552);  //  8,388,608 B
    __bf16* vt_ws = (__bf16*)(ws + 28508160);  //  8,388,608 B
    __bf16* vals  = (__bf16*)(ws + 36896768);  //  8,388,608 B  (total ~45.3 MB)

    k_convert<<<22912, 256, 0, stream>>>(x, inp, Wqkv, Wo, xc, wq, wo);
    k_qkv_gemm<<<dim3(128, 24), 256, 0, stream>>>(xc, wq, bqkv, q_ws, k_ws, vt_ws);
    k_attn<<<4096, 256, 0, stream>>>(q_ws, k_ws, vt_ws, out_att, vals);
    k_out_gemm<<<dim3(128, 8), 256, 0, stream>>>(vals, wo, bo, out_o);
}

// Round 3
// 203.545 us; speedup vs baseline: 1.5101x; 1.0864x over previous
//
#include <hip/hip_runtime.h>

typedef __bf16 bf16x8 __attribute__((ext_vector_type(8)));
typedef __bf16 bf16x4 __attribute__((ext_vector_type(4)));
typedef float f32x4 __attribute__((ext_vector_type(4)));

#define MFMA16(a,b,c) __builtin_amdgcn_mfma_f32_16x16x32_bf16((a),(b),(c),0,0,0)

// Problem constants: B=8 S=1024 IN=512 ORIG=64 E=512 H=8 hd=64
// xc: [8192][576]  Wqkv: [1536][576]  Wo: [512][512]
// q_ws/k_ws: [64(bh)][1024(s)][64(d)] bf16 ; vt_ws: [64(bh)][64(d)][1024(s)] bf16
// values: [8192][512] bf16

__global__ __launch_bounds__(256) void k_convert(
    const float* __restrict__ x, const float* __restrict__ inp,
    const float* __restrict__ Wqkv, const float* __restrict__ Wo,
    __bf16* __restrict__ xc, __bf16* __restrict__ wq, __bf16* __restrict__ wo)
{
    unsigned i = blockIdx.x * 256u + threadIdx.x;
    const unsigned n1 = 8192u * 576u;
    const unsigned n2 = 1536u * 576u;
    if (i < n1) {
        unsigned m = i / 576u, k = i - m * 576u;
        float v = (k < 512u) ? x[(size_t)m * 512u + k] : inp[(size_t)m * 64u + (k - 512u)];
        xc[i] = (__bf16)v;
    } else if (i < n1 + n2) {
        wq[i - n1] = (__bf16)Wqkv[i - n1];
    } else {
        wo[i - n1 - n2] = (__bf16)Wo[i - n1 - n2];
    }
}

// ---------------- QKV GEMM: [8192x576] @ [576x1536] -> scatter q/k/vt ----------------
__global__ __launch_bounds__(256) void k_qkv_gemm(
    const __bf16* __restrict__ A, const __bf16* __restrict__ W,
    const float* __restrict__ bias,
    __bf16* __restrict__ q_ws, __bf16* __restrict__ k_ws, __bf16* __restrict__ vt_ws)
{
    const int K = 576;
    __shared__ __align__(16) __bf16 As[64][40];
    __shared__ __align__(16) __bf16 Bs[64][40];
    int m0 = blockIdx.x * 64, n0 = blockIdx.y * 64;
    int t = threadIdx.x, w = t >> 6, l = t & 63;
    int srow = t >> 2, scol = (t & 3) * 8;
    f32x4 acc[4] = {};
    for (int k0 = 0; k0 < K; k0 += 32) {
        *(bf16x8*)&As[srow][scol] = *(const bf16x8*)&A[(size_t)(m0 + srow) * K + k0 + scol];
        *(bf16x8*)&Bs[srow][scol] = *(const bf16x8*)&W[(size_t)(n0 + srow) * K + k0 + scol];
        __syncthreads();
        bf16x8 af = *(const bf16x8*)&As[w * 16 + (l & 15)][(l >> 4) * 8];
#pragma unroll
        for (int nti = 0; nti < 4; ++nti) {
            bf16x8 bfr = *(const bf16x8*)&Bs[nti * 16 + (l & 15)][(l >> 4) * 8];
            acc[nti] = MFMA16(af, bfr, acc[nti]);
        }
        __syncthreads();
    }
    int col = l & 15, rb = (l >> 4) * 4;
#pragma unroll
    for (int nti = 0; nti < 4; ++nti) {
        int n = n0 + nti * 16 + col;
        int h = n / 192, jj = n % 192, part = jj >> 6, d = jj & 63;
#pragma unroll
        for (int j = 0; j < 4; ++j) {
            int m = m0 + w * 16 + rb + j;
            float v = acc[nti][j] + bias[n];
            int b = m >> 10, s = m & 1023;
            size_t bh = (size_t)(b * 8 + h);
            if (part == 0)      q_ws[(bh * 1024 + s) * 64 + d] = (__bf16)(v * 0.125f);
            else if (part == 1) k_ws[(bh * 1024 + s) * 64 + d] = (__bf16)v;
            else                vt_ws[(bh * 64 + d) * 1024 + s] = (__bf16)v;
        }
    }
}

// ---------------- fused attention v3: register logits, barrier-free softmax+PV ----------------
__global__ __launch_bounds__(256) void k_attn(
    const __bf16* __restrict__ q_ws, const __bf16* __restrict__ k_ws,
    const __bf16* __restrict__ vt_ws,
    float* __restrict__ att_out, __bf16* __restrict__ values)
{
    __shared__ __align__(16) __bf16 Qs[16][72];      //  2,304 B
    __shared__ __align__(16) __bf16 Ps[4][16][264];  // 33,792 B (row stride 528B: 2-way max)
    __shared__ __align__(16) float Ored[4][16][64];  // 16,384 B  -> total ~52.5 KB, 3 blk/CU

    // bijective XCD swizzle: XCD x handles bh in [x*8, x*8+8)
    int bid = blockIdx.x;                  // grid = 4096 (64 bh x 64 q-tiles)
    int nid = (bid & 7) * 512 + (bid >> 3);
    int bh = nid >> 6, qt = nid & 63;
    int q0 = qt * 16;
    int t = threadIdx.x, w = t >> 6, l = t & 63;
    int lo = l & 15, hi = l >> 4;

    if (t < 128) {  // stage Q tile [16][64]
        int r = t >> 3, c = (t & 7) * 8;
        *(bf16x8*)&Qs[r][c] = *(const bf16x8*)&q_ws[((size_t)bh * 1024 + q0 + r) * 64 + c];
    }
    __syncthreads();

    bf16x8 qa0 = *(const bf16x8*)&Qs[lo][hi * 8];
    bf16x8 qa1 = *(const bf16x8*)&Qs[lo][32 + hi * 8];

    // QK^T into registers: lane holds S[q0 + hi*4 + j][w*256 + ct*16 + lo], ct=0..15
    const __bf16* Kb = k_ws + (size_t)bh * 65536;
    f32x4 acc[16];
#pragma unroll
    for (int ct = 0; ct < 16; ++ct) {
        const __bf16* kp = Kb + (size_t)(w * 256 + ct * 16 + lo) * 64 + hi * 8;
        bf16x8 kb0 = *(const bf16x8*)kp;
        bf16x8 kb1 = *(const bf16x8*)(kp + 32);
        f32x4 a = {};
        a = MFMA16(qa0, kb0, a);
        a = MFMA16(qa1, kb1, a);
        acc[ct] = a;
    }

    // softmax over full rows: lane-local over 16 ct, then across the 16-lane lo group.
    // NOTE: this wave only has cols [w*256, w*256+256) -> rows are SPLIT across waves? No:
    // each wave covers a distinct 256-col slice of the SAME 16 rows, so the row max/sum
    // must combine across waves. Use Ored as a tiny cross-wave scratch for (mx,sum).
    f32x4 mx = acc[0];
#pragma unroll
    for (int ct = 1; ct < 16; ++ct) {
#pragma unroll
        for (int j = 0; j < 4; ++j) mx[j] = fmaxf(mx[j], acc[ct][j]);
    }
#pragma unroll
    for (int off = 1; off < 16; off <<= 1) {
#pragma unroll
        for (int j = 0; j < 4; ++j) mx[j] = fmaxf(mx[j], __shfl_xor(mx[j], off));
    }
    // cross-wave max: Ored[w][hi*4+j][0..] reuse as scratch: [w][r] pairs
    if (lo == 0) {
#pragma unroll
        for (int j = 0; j < 4; ++j) Ored[w][hi * 4 + j][0] = mx[j];
    }
    __syncthreads();
#pragma unroll
    for (int j = 0; j < 4; ++j) {
        int r = hi * 4 + j;
        mx[j] = fmaxf(fmaxf(Ored[0][r][0], Ored[1][r][0]),
                      fmaxf(Ored[2][r][0], Ored[3][r][0]));
    }
    f32x4 sum = {};
#pragma unroll
    for (int ct = 0; ct < 16; ++ct) {
#pragma unroll
        for (int j = 0; j < 4; ++j) {
            acc[ct][j] = __expf(acc[ct][j] - mx[j]);
            sum[j] += acc[ct][j];
        }
    }
#pragma unroll
    for (int off = 1; off < 16; off <<= 1) {
#pragma unroll
        for (int j = 0; j < 4; ++j) sum[j] += __shfl_xor(sum[j], off);
    }
    __syncthreads();   // Ored scratch reuse hazard fence
    if (lo == 0) {
#pragma unroll
        for (int j = 0; j < 4; ++j) Ored[w][hi * 4 + j][1] = sum[j];
    }
    __syncthreads();
    f32x4 inv;
#pragma unroll
    for (int j = 0; j < 4; ++j) {
        int r = hi * 4 + j;
        inv[j] = 1.f / (Ored[0][r][1] + Ored[1][r][1] + Ored[2][r][1] + Ored[3][r][1]);
    }

    // write probs: f32 -> global (nontemporal), bf16 -> wave-private LDS for PV
    float* gout = att_out + ((size_t)bh * 1024 + q0) * 1024 + w * 256;
#pragma unroll
    for (int ct = 0; ct < 16; ++ct) {
#pragma unroll
        for (int j = 0; j < 4; ++j) {
            float p = acc[ct][j] * inv[j];
            __builtin_nontemporal_store(p, &gout[(size_t)(hi * 4 + j) * 1024 + ct * 16 + lo]);
            Ps[w][hi * 4 + j][ct * 16 + lo] = (__bf16)p;
        }
    }
    asm volatile("s_waitcnt lgkmcnt(0)" ::: "memory");
    __builtin_amdgcn_sched_barrier(0);

    // PV: partial over this wave's 256-k slice; A = Ps[w], B = V^T
    const __bf16* Vb = vt_ws + (size_t)bh * 65536 + w * 256;
    f32x4 oacc[4] = {};
#pragma unroll
    for (int kc = 0; kc < 8; ++kc) {
        bf16x8 pa = *(const bf16x8*)&Ps[w][lo][kc * 32 + hi * 8];
#pragma unroll
        for (int dt = 0; dt < 4; ++dt) {
            bf16x8 vb = *(const bf16x8*)(Vb + (size_t)(dt * 16 + lo) * 1024 + kc * 32 + hi * 8);
            oacc[dt] = MFMA16(pa, vb, oacc[dt]);
        }
    }
#pragma unroll
    for (int dt = 0; dt < 4; ++dt)
#pragma unroll
        for (int j = 0; j < 4; ++j)
            Ored[w][hi * 4 + j][dt * 16 + lo] = oacc[dt][j];
    __syncthreads();

    // cross-wave reduce + store values: 1024 outputs, thread t -> (r, d..d+3)
    {
        int r = t >> 4, d = (t & 15) * 4;
        f32x4 s0 = *(f32x4*)&Ored[0][r][d];
        f32x4 s1 = *(f32x4*)&Ored[1][r][d];
        f32x4 s2 = *(f32x4*)&Ored[2][r][d];
        f32x4 s3 = *(f32x4*)&Ored[3][r][d];
        f32x4 o = (s0 + s1) + (s2 + s3);
        bf16x4 ob;
        ob[0] = (__bf16)o[0]; ob[1] = (__bf16)o[1];
        ob[2] = (__bf16)o[2]; ob[3] = (__bf16)o[3];
        int b = bh >> 3, h = bh & 7;
        *(bf16x4*)&values[((size_t)b * 1024 + q0 + r) * 512 + h * 64 + d] = ob;
    }
}

// ---------------- output GEMM: [8192x512] @ [512x512] + bias -> o ----------------
__global__ __launch_bounds__(256) void k_out_gemm(
    const __bf16* __restrict__ A, const __bf16* __restrict__ W,
    const float* __restrict__ bias, float* __restrict__ out)
{
    const int K = 512;
    __shared__ __align__(16) __bf16 As[64][40];
    __shared__ __align__(16) __bf16 Bs[64][40];
    int m0 = blockIdx.x * 64, n0 = blockIdx.y * 64;
    int t = threadIdx.x, w = t >> 6, l = t & 63;
    int srow = t >> 2, scol = (t & 3) * 8;
    f32x4 acc[4] = {};
    for (int k0 = 0; k0 < K; k0 += 32) {
        *(bf16x8*)&As[srow][scol] = *(const bf16x8*)&A[(size_t)(m0 + srow) * K + k0 + scol];
        *(bf16x8*)&Bs[srow][scol] = *(const bf16x8*)&W[(size_t)(n0 + srow) * K + k0 + scol];
        __syncthreads();
        bf16x8 af = *(const bf16x8*)&As[w * 16 + (l & 15)][(l >> 4) * 8];
#pragma unroll
        for (int nti = 0; nti < 4; ++nti) {
            bf16x8 bfr = *(const bf16x8*)&Bs[nti * 16 + (l & 15)][(l >> 4) * 8];
            acc[nti] = MFMA16(af, bfr, acc[nti]);
        }
        __syncthreads();
    }
    int col = l & 15, rb = (l >> 4) * 4;
#pragma unroll
    for (int nti = 0; nti < 4; ++nti) {
        int n = n0 + nti * 16 + col;
        float bn = bias[n];
#pragma unroll
        for (int j = 0; j < 4; ++j) {
            int m = m0 + w * 16 + rb + j;
            out[(size_t)m * 512 + n] = acc[nti][j] + bn;
        }
    }
}

extern "C" void kernel_launch(void* const* d_in, const int* in_sizes, int n_in,
                              void* d_out, int out_size, void* d_ws, size_t ws_size,
                              hipStream_t stream)
{
    const float* x    = (const float*)d_in[0];
    const float* inp  = (const float*)d_in[1];
    const float* Wqkv = (const float*)d_in[2];
    const float* bqkv = (const float*)d_in[3];
    const float* Wo   = (const float*)d_in[4];
    const float* bo   = (const float*)d_in[5];

    float* out_o   = (float*)d_out;                    // [8,1024,512]
    float* out_att = out_o + (size_t)8 * 1024 * 512;   // [8,8,1024,1024]

    char* ws = (char*)d_ws;
    __bf16* xc    = (__bf16*)(ws + 0);
    __bf16* wq    = (__bf16*)(ws + 9437184);
    __bf16* wo    = (__bf16*)(ws + 11206656);
    __bf16* q_ws  = (__bf16*)(ws + 11730944);
    __bf16* k_ws  = (__bf16*)(ws + 20119552);
    __bf16* vt_ws = (__bf16*)(ws + 28508160);
    __bf16* vals  = (__bf16*)(ws + 36896768);

    k_convert<<<22912, 256, 0, stream>>>(x, inp, Wqkv, Wo, xc, wq, wo);
    k_qkv_gemm<<<dim3(128, 24), 256, 0, stream>>>(xc, wq, bqkv, q_ws, k_ws, vt_ws);
    k_attn<<<4096, 256, 0, stream>>>(q_ws, k_ws, vt_ws, out_att, vals);
    k_out_gemm<<<dim3(128, 8), 256, 0, stream>>>(vals, wo, bo, out_o);
}